// Round 1
// baseline (3451.582 us; speedup 1.0000x reference)
//
#include <hip/hip_runtime.h>
#include <hip/hip_bf16.h>
#include <math.h>

#define N_NODES 100000
#define N_EDGES 1600000

// ---------------- graph prep ----------------

__global__ void k_count(const int* __restrict__ src, const int* __restrict__ dst,
                        int* __restrict__ deg_out, int* __restrict__ deg_in) {
  int i = blockIdx.x * blockDim.x + threadIdx.x;
  int stride = gridDim.x * blockDim.x;
  for (; i < N_EDGES; i += stride) {
    atomicAdd(&deg_out[src[i]], 1);
    atomicAdd(&deg_in[dst[i]], 1);
  }
}

__global__ void k_norms(const int* __restrict__ deg_out, const int* __restrict__ deg_in,
                        float* __restrict__ norm_out, float* __restrict__ norm_in) {
  int i = blockIdx.x * blockDim.x + threadIdx.x;
  if (i < N_NODES) {
    int a = deg_out[i], b = deg_in[i];
    norm_out[i] = a > 0 ? rsqrtf((float)a) : 0.f;
    norm_in[i]  = b > 0 ? rsqrtf((float)b) : 0.f;
  }
}

// single-block exclusive scan of deg_in -> row_ptr[0..N]
__global__ __launch_bounds__(1024) void k_scan(const int* __restrict__ deg,
                                               int* __restrict__ row_ptr) {
  __shared__ int buf[1024];
  __shared__ int carry_s;
  int t = threadIdx.x;
  if (t == 0) { carry_s = 0; row_ptr[0] = 0; }
  __syncthreads();
  for (int base = 0; base < N_NODES; base += 1024) {
    int x = (base + t < N_NODES) ? deg[base + t] : 0;
    buf[t] = x;
    __syncthreads();
    for (int offx = 1; offx < 1024; offx <<= 1) {
      int v = (t >= offx) ? buf[t - offx] : 0;
      __syncthreads();
      buf[t] += v;
      __syncthreads();
    }
    int incl = buf[t];
    int c = carry_s;
    __syncthreads();
    if (base + t < N_NODES) row_ptr[base + t + 1] = c + incl;
    if (t == 0) carry_s = c + buf[1023];
    __syncthreads();
  }
}

__global__ void k_fill(const int* __restrict__ src, const int* __restrict__ dst,
                       const int* __restrict__ row_ptr, int* __restrict__ cursor,
                       int* __restrict__ csr_src) {
  int i = blockIdx.x * blockDim.x + threadIdx.x;
  int stride = gridDim.x * blockDim.x;
  for (; i < N_EDGES; i += stride) {
    int d = dst[i];
    int p = atomicAdd(&cursor[d], 1);
    csr_src[row_ptr[d] + p] = src[i];
  }
}

__global__ void k_padw(const float* __restrict__ W_out, float* __restrict__ Wpad) {
  int i = blockIdx.x * blockDim.x + threadIdx.x;
  if (i < 256 * 64) {
    int k = i >> 6, c = i & 63;
    Wpad[i] = (c < 40) ? W_out[k * 40 + c] : 0.f;
  }
}

// ---------------- GEMM: C[nrows x ncols] = (A * rowscale) @ W ----------------
// tile 64x64, block 256 threads, 4x4 per thread, K multiple of 16

__global__ __launch_bounds__(256) void k_gemm(const float* __restrict__ A, int K,
                                              const float* __restrict__ W, int ldw,
                                              const float* __restrict__ rowscale,
                                              float* __restrict__ C, int ldc, int nrows) {
  __shared__ float As[16][68];  // [k][row] (transposed), +4 pad
  __shared__ float Wsb[16][68]; // [k][col], +4 pad
  int t = threadIdx.x;
  int tx = t & 15, ty = t >> 4;
  int rowBase = blockIdx.x * 64;
  int colBase = blockIdx.y * 64;

  int la_row = t >> 2;          // 0..63
  int la_k4  = (t & 3) * 4;     // 0,4,8,12
  int lw_k   = t >> 4;          // 0..15
  int lw_c4  = (t & 15) * 4;    // 0..60

  int ga_row = rowBase + la_row;
  float rs = (ga_row < nrows) ? rowscale[ga_row] : 0.f;
  const float* Arow = A + (size_t)ga_row * K;

  float acc[4][4];
#pragma unroll
  for (int i = 0; i < 4; ++i)
#pragma unroll
    for (int j = 0; j < 4; ++j) acc[i][j] = 0.f;

  for (int k0 = 0; k0 < K; k0 += 16) {
    float4 a = make_float4(0.f, 0.f, 0.f, 0.f);
    if (ga_row < nrows) a = *(const float4*)(Arow + k0 + la_k4);
    a.x *= rs; a.y *= rs; a.z *= rs; a.w *= rs;
    float4 w = *(const float4*)(W + (size_t)(k0 + lw_k) * ldw + colBase + lw_c4);
    As[la_k4 + 0][la_row] = a.x;
    As[la_k4 + 1][la_row] = a.y;
    As[la_k4 + 2][la_row] = a.z;
    As[la_k4 + 3][la_row] = a.w;
    *(float4*)&Wsb[lw_k][lw_c4] = w;
    __syncthreads();
#pragma unroll
    for (int k = 0; k < 16; ++k) {
      float4 av = *(const float4*)&As[k][ty * 4];
      float4 wv = *(const float4*)&Wsb[k][tx * 4];
      float a0 = av.x, a1 = av.y, a2 = av.z, a3 = av.w;
      float w0 = wv.x, w1 = wv.y, w2 = wv.z, w3 = wv.w;
      acc[0][0] = fmaf(a0, w0, acc[0][0]); acc[0][1] = fmaf(a0, w1, acc[0][1]);
      acc[0][2] = fmaf(a0, w2, acc[0][2]); acc[0][3] = fmaf(a0, w3, acc[0][3]);
      acc[1][0] = fmaf(a1, w0, acc[1][0]); acc[1][1] = fmaf(a1, w1, acc[1][1]);
      acc[1][2] = fmaf(a1, w2, acc[1][2]); acc[1][3] = fmaf(a1, w3, acc[1][3]);
      acc[2][0] = fmaf(a2, w0, acc[2][0]); acc[2][1] = fmaf(a2, w1, acc[2][1]);
      acc[2][2] = fmaf(a2, w2, acc[2][2]); acc[2][3] = fmaf(a2, w3, acc[2][3]);
      acc[3][0] = fmaf(a3, w0, acc[3][0]); acc[3][1] = fmaf(a3, w1, acc[3][1]);
      acc[3][2] = fmaf(a3, w2, acc[3][2]); acc[3][3] = fmaf(a3, w3, acc[3][3]);
    }
    __syncthreads();
  }

#pragma unroll
  for (int i = 0; i < 4; ++i) {
    int r = rowBase + ty * 4 + i;
    if (r < nrows) {
      float4 o = make_float4(acc[i][0], acc[i][1], acc[i][2], acc[i][3]);
      *(float4*)(C + (size_t)r * ldc + colBase + tx * 4) = o;
    }
  }
}

// ---------------- CSR aggregation, 256-dim, fused norm+bias+relu+JK ----------------

__global__ __launch_bounds__(256) void k_agg(const float* __restrict__ proj,
                                             const int* __restrict__ row_ptr,
                                             const int* __restrict__ csr_src,
                                             const float* __restrict__ norm_in,
                                             const float* __restrict__ bias,
                                             float* __restrict__ h_out,
                                             float* __restrict__ jk, int mode) {
  __shared__ int elist[256];
  int n = blockIdx.x;
  int c = threadIdx.x;
  int s = row_ptr[n], e = row_ptr[n + 1];
  float acc0 = 0.f, acc1 = 0.f;
  for (int basei = s; basei < e; basei += 256) {
    int cnt = min(256, e - basei);
    __syncthreads();
    if (c < cnt) elist[c] = csr_src[basei + c];
    __syncthreads();
    int j = 0;
    for (; j + 1 < cnt; j += 2) {
      int u0 = elist[j], u1 = elist[j + 1];
      acc0 += proj[(size_t)u0 * 256 + c];
      acc1 += proj[(size_t)u1 * 256 + c];
    }
    if (j < cnt) acc0 += proj[(size_t)elist[j] * 256 + c];
  }
  float v = (acc0 + acc1) * norm_in[n] + bias[c];
  v = fmaxf(v, 0.f);
  h_out[(size_t)n * 256 + c] = v;
  if (mode == 0) jk[(size_t)n * 256 + c] = v;
  else           jk[(size_t)n * 256 + c] = fmaxf(jk[(size_t)n * 256 + c], v);
}

// ---------------- final 40-dim aggregation + log_softmax ----------------

__global__ __launch_bounds__(64) void k_agg_out(const float* __restrict__ proj,
                                                const int* __restrict__ row_ptr,
                                                const int* __restrict__ csr_src,
                                                const float* __restrict__ norm_in,
                                                const float* __restrict__ b_out,
                                                float* __restrict__ out) {
  int n = blockIdx.x;
  int c = threadIdx.x;  // 64 threads, cols 0..39 live
  int s = row_ptr[n], e = row_ptr[n + 1];
  float acc = 0.f;
  for (int i = s; i < e; ++i) {
    acc += proj[(size_t)csr_src[i] * 64 + c];
  }
  float v = acc * norm_in[n] + ((c < 40) ? b_out[c] : 0.f);
  float vm = (c < 40) ? v : -3.0e38f;
  float m = vm;
#pragma unroll
  for (int o = 32; o > 0; o >>= 1) m = fmaxf(m, __shfl_xor(m, o, 64));
  float ex = (c < 40) ? __expf(v - m) : 0.f;
  float ssum = ex;
#pragma unroll
  for (int o = 32; o > 0; o >>= 1) ssum += __shfl_xor(ssum, o, 64);
  float lse = m + logf(ssum);
  if (c < 40) out[(size_t)n * 40 + c] = v - lse;
}

// ---------------- launch ----------------

extern "C" void kernel_launch(void* const* d_in, const int* in_sizes, int n_in,
                              void* d_out, int out_size, void* d_ws, size_t ws_size,
                              hipStream_t stream) {
  const float* feats = (const float*)d_in[0];
  const int*   src   = (const int*)d_in[1];
  const int*   dst   = (const int*)d_in[2];
  const float* W0    = (const float*)d_in[3];
  const float* b0    = (const float*)d_in[4];
  const float* Ws    = (const float*)d_in[5];
  const float* bs    = (const float*)d_in[6];
  const float* W_out = (const float*)d_in[7];
  const float* b_out = (const float*)d_in[8];
  float* out = (float*)d_out;

  char* base = (char*)d_ws;
  size_t off = 0;
  auto alloc = [&](size_t bytes) -> void* {
    off = (off + 255) & ~(size_t)255;
    void* r = base + off;
    off += bytes;
    return r;
  };
  float* norm_out = (float*)alloc((size_t)N_NODES * 4);
  float* norm_in  = (float*)alloc((size_t)N_NODES * 4);
  int*   deg_out  = (int*)alloc((size_t)N_NODES * 4);
  int*   deg_in   = (int*)alloc((size_t)N_NODES * 4);
  int*   cursor   = (int*)alloc((size_t)N_NODES * 4);
  int*   row_ptr  = (int*)alloc((size_t)(N_NODES + 1) * 4);
  int*   csr_src  = (int*)alloc((size_t)N_EDGES * 4);
  float* Wpad     = (float*)alloc((size_t)256 * 64 * 4);
  float* proj40   = (float*)alloc((size_t)N_NODES * 64 * 4);
  float* bufA     = (float*)alloc((size_t)N_NODES * 256 * 4);
  float* bufB     = (float*)alloc((size_t)N_NODES * 256 * 4);
  float* jk       = (float*)alloc((size_t)N_NODES * 256 * 4);
  (void)ws_size; (void)in_sizes; (void)n_in; (void)out_size;

  hipMemsetAsync(deg_out, 0, (size_t)N_NODES * 4, stream);
  hipMemsetAsync(deg_in,  0, (size_t)N_NODES * 4, stream);
  hipMemsetAsync(cursor,  0, (size_t)N_NODES * 4, stream);

  k_count<<<2048, 256, 0, stream>>>(src, dst, deg_out, deg_in);
  k_norms<<<(N_NODES + 255) / 256, 256, 0, stream>>>(deg_out, deg_in, norm_out, norm_in);
  k_scan<<<1, 1024, 0, stream>>>(deg_in, row_ptr);
  k_fill<<<2048, 256, 0, stream>>>(src, dst, row_ptr, cursor, csr_src);
  k_padw<<<64, 256, 0, stream>>>(W_out, Wpad);

  dim3 gg((N_NODES + 63) / 64, 4);
  // layer 0 (K=512)
  k_gemm<<<gg, 256, 0, stream>>>(feats, 512, W0, 256, norm_out, bufB, 256, N_NODES);
  k_agg<<<N_NODES, 256, 0, stream>>>(bufB, row_ptr, csr_src, norm_in, b0, bufA, jk, 0);
  // layers 1..5 (K=256)
  for (int l = 0; l < 5; ++l) {
    k_gemm<<<gg, 256, 0, stream>>>(bufA, 256, Ws + (size_t)l * 256 * 256, 256,
                                   norm_out, bufB, 256, N_NODES);
    k_agg<<<N_NODES, 256, 0, stream>>>(bufB, row_ptr, csr_src, norm_in,
                                       bs + (size_t)l * 256, bufA, jk, 1);
  }
  // final: jk @ W_out (padded to 64 cols), aggregate, log_softmax
  dim3 gf((N_NODES + 63) / 64, 1);
  k_gemm<<<gf, 256, 0, stream>>>(jk, 256, Wpad, 64, norm_out, proj40, 64, N_NODES);
  k_agg_out<<<N_NODES, 64, 0, stream>>>(proj40, row_ptr, csr_src, norm_in, b_out, out);
}

// Round 2
// 2792.366 us; speedup vs baseline: 1.2361x; 1.2361x over previous
//
#include <hip/hip_runtime.h>
#include <hip/hip_bf16.h>
#include <math.h>

#define N_NODES 100000
#define N_EDGES 1600000

typedef short s16x8 __attribute__((ext_vector_type(8)));
typedef float f32x4 __attribute__((ext_vector_type(4)));
typedef unsigned short u16;
typedef u16 u16x8 __attribute__((ext_vector_type(8)));

__device__ __forceinline__ u16 f2bf_rn(float f) {
  union { float f; unsigned u; } x; x.f = f;
  unsigned u = x.u + 0x7fffu + ((x.u >> 16) & 1u);
  return (u16)(u >> 16);
}

// ---------------- graph prep ----------------

__global__ void k_count(const int* __restrict__ src, const int* __restrict__ dst,
                        int* __restrict__ deg_out, int* __restrict__ deg_in) {
  int i = blockIdx.x * blockDim.x + threadIdx.x;
  int stride = gridDim.x * blockDim.x;
  for (; i < N_EDGES; i += stride) {
    atomicAdd(&deg_out[src[i]], 1);
    atomicAdd(&deg_in[dst[i]], 1);
  }
}

__global__ void k_norms(const int* __restrict__ deg_out, const int* __restrict__ deg_in,
                        float* __restrict__ norm_out, float* __restrict__ norm_in) {
  int i = blockIdx.x * blockDim.x + threadIdx.x;
  if (i < N_NODES) {
    int a = deg_out[i], b = deg_in[i];
    norm_out[i] = a > 0 ? rsqrtf((float)a) : 0.f;
    norm_in[i]  = b > 0 ? rsqrtf((float)b) : 0.f;
  }
}

// single-block exclusive scan of deg_in -> row_ptr[0..N]
__global__ __launch_bounds__(1024) void k_scan(const int* __restrict__ deg,
                                               int* __restrict__ row_ptr) {
  __shared__ int buf[1024];
  __shared__ int carry_s;
  int t = threadIdx.x;
  if (t == 0) { carry_s = 0; row_ptr[0] = 0; }
  __syncthreads();
  for (int base = 0; base < N_NODES; base += 1024) {
    int x = (base + t < N_NODES) ? deg[base + t] : 0;
    buf[t] = x;
    __syncthreads();
    for (int offx = 1; offx < 1024; offx <<= 1) {
      int v = (t >= offx) ? buf[t - offx] : 0;
      __syncthreads();
      buf[t] += v;
      __syncthreads();
    }
    int incl = buf[t];
    int c = carry_s;
    __syncthreads();
    if (base + t < N_NODES) row_ptr[base + t + 1] = c + incl;
    if (t == 0) carry_s = c + buf[1023];
    __syncthreads();
  }
}

__global__ void k_fill(const int* __restrict__ src, const int* __restrict__ dst,
                       const int* __restrict__ row_ptr, int* __restrict__ cursor,
                       int* __restrict__ csr_src) {
  int i = blockIdx.x * blockDim.x + threadIdx.x;
  int stride = gridDim.x * blockDim.x;
  for (; i < N_EDGES; i += stride) {
    int d = dst[i];
    int p = atomicAdd(&cursor[d], 1);
    csr_src[row_ptr[d] + p] = src[i];
  }
}

// transpose + hi/lo split of a weight matrix: W[K][N] f32 -> Wt_hi/lo[NB][K] bf16
__global__ void k_wsplit(const float* __restrict__ W, int K, int N, int NB,
                         u16* __restrict__ Wth, u16* __restrict__ Wtl) {
  int i = blockIdx.x * blockDim.x + threadIdx.x;
  if (i >= NB * K) return;
  int col = i / K, k = i - col * K;
  float v = (col < N) ? W[(size_t)k * N + col] : 0.f;
  union { float f; unsigned u; } x; x.f = v;
  u16 h = (u16)(x.u >> 16);
  union { unsigned u; float f; } hf; hf.u = (unsigned)h << 16;
  Wth[i] = h;
  Wtl[i] = f2bf_rn(v - hf.f);
}

// ---------------- MFMA GEMM: C = (A * rowscale) @ W, split-bf16 3-term ----------------
// A f32 [M][K] (split in-register at staging), W pre-transposed+split bf16 [NB][K].
// tile 128x128, BK=32, 256 threads = 4 waves (2x2), each wave 4x4 frags of 16x16x32.

__global__ __launch_bounds__(256) void k_gemm_mfma(
    const float* __restrict__ A, int K,
    const u16* __restrict__ Bh, const u16* __restrict__ Bl,
    const float* __restrict__ rowscale,
    float* __restrict__ C, int ldc, int M, int Ncols) {
  __shared__ u16 sAh[128][40];
  __shared__ u16 sAl[128][40];
  __shared__ u16 sBh[128][40];
  __shared__ u16 sBl[128][40];

  int t = threadIdx.x;
  int rowBase = blockIdx.x * 128;
  int colBase = blockIdx.y * 128;

  // staging assignment: chunks t and t+256; chunk c -> row=c>>2, q=c&3 (8 elts)
  int row0 = t >> 2, q8 = (t & 3) * 8;
  int gr0 = min(rowBase + row0, M - 1);
  int gr1 = min(rowBase + row0 + 64, M - 1);
  float rs0 = rowscale[gr0], rs1 = rowscale[gr1];
  const float* A0 = A + (size_t)gr0 * K;
  const float* A1 = A + (size_t)gr1 * K;
  const u16* B0h = Bh + (size_t)(colBase + row0) * K;
  const u16* B0l = Bl + (size_t)(colBase + row0) * K;
  const u16* B1h = Bh + (size_t)(colBase + row0 + 64) * K;
  const u16* B1l = Bl + (size_t)(colBase + row0 + 64) * K;

  // wave/lane decomposition
  int w = t >> 6, l = t & 63;
  int wr = (w >> 1) * 64, wc = (w & 1) * 64;
  int lr = l & 15;
  int kb = (l >> 4) * 8;
  int crow = (l >> 4) * 4;

  f32x4 acc[4][4];
#pragma unroll
  for (int r = 0; r < 4; ++r)
#pragma unroll
    for (int c = 0; c < 4; ++c) acc[r][c] = (f32x4)(0.f);

  for (int k0 = 0; k0 < K; k0 += 32) {
    __syncthreads();
    // ---- stage A (f32 -> split bf16) ----
    {
      const float* p = A0 + k0 + q8;
      float4 v0 = *(const float4*)p;
      float4 v1 = *(const float4*)(p + 4);
      float vv[8] = {v0.x * rs0, v0.y * rs0, v0.z * rs0, v0.w * rs0,
                     v1.x * rs0, v1.y * rs0, v1.z * rs0, v1.w * rs0};
      u16x8 hi, lo;
#pragma unroll
      for (int i = 0; i < 8; ++i) {
        union { float f; unsigned u; } x; x.f = vv[i];
        hi[i] = (u16)(x.u >> 16);
        union { unsigned u; float f; } hf; hf.u = x.u & 0xffff0000u;
        lo[i] = f2bf_rn(vv[i] - hf.f);
      }
      *(u16x8*)&sAh[row0][q8] = hi;
      *(u16x8*)&sAl[row0][q8] = lo;
    }
    {
      const float* p = A1 + k0 + q8;
      float4 v0 = *(const float4*)p;
      float4 v1 = *(const float4*)(p + 4);
      float vv[8] = {v0.x * rs1, v0.y * rs1, v0.z * rs1, v0.w * rs1,
                     v1.x * rs1, v1.y * rs1, v1.z * rs1, v1.w * rs1};
      u16x8 hi, lo;
#pragma unroll
      for (int i = 0; i < 8; ++i) {
        union { float f; unsigned u; } x; x.f = vv[i];
        hi[i] = (u16)(x.u >> 16);
        union { unsigned u; float f; } hf; hf.u = x.u & 0xffff0000u;
        lo[i] = f2bf_rn(vv[i] - hf.f);
      }
      *(u16x8*)&sAh[row0 + 64][q8] = hi;
      *(u16x8*)&sAl[row0 + 64][q8] = lo;
    }
    // ---- stage B (bf16 direct) ----
    *(u16x8*)&sBh[row0][q8]      = *(const u16x8*)(B0h + k0 + q8);
    *(u16x8*)&sBl[row0][q8]      = *(const u16x8*)(B0l + k0 + q8);
    *(u16x8*)&sBh[row0 + 64][q8] = *(const u16x8*)(B1h + k0 + q8);
    *(u16x8*)&sBl[row0 + 64][q8] = *(const u16x8*)(B1l + k0 + q8);
    __syncthreads();

    // ---- fragments ----
    s16x8 ah[4], al[4], bh[4], bl[4];
#pragma unroll
    for (int r = 0; r < 4; ++r) {
      ah[r] = *(const s16x8*)&sAh[wr + r * 16 + lr][kb];
      al[r] = *(const s16x8*)&sAl[wr + r * 16 + lr][kb];
    }
#pragma unroll
    for (int c = 0; c < 4; ++c) {
      bh[c] = *(const s16x8*)&sBh[wc + c * 16 + lr][kb];
      bl[c] = *(const s16x8*)&sBl[wc + c * 16 + lr][kb];
    }
#pragma unroll
    for (int r = 0; r < 4; ++r)
#pragma unroll
      for (int c = 0; c < 4; ++c) {
        acc[r][c] = __builtin_amdgcn_mfma_f32_16x16x32_bf16(ah[r], bh[c], acc[r][c], 0, 0, 0);
        acc[r][c] = __builtin_amdgcn_mfma_f32_16x16x32_bf16(ah[r], bl[c], acc[r][c], 0, 0, 0);
        acc[r][c] = __builtin_amdgcn_mfma_f32_16x16x32_bf16(al[r], bh[c], acc[r][c], 0, 0, 0);
      }
  }

  // ---- store ----
#pragma unroll
  for (int r = 0; r < 4; ++r)
#pragma unroll
    for (int c = 0; c < 4; ++c) {
      int col = colBase + wc + c * 16 + lr;
      if (col < Ncols) {
#pragma unroll
        for (int j = 0; j < 4; ++j) {
          int row = rowBase + wr + r * 16 + crow + j;
          if (row < M) C[(size_t)row * ldc + col] = acc[r][c][j];
        }
      }
    }
}

// ---------------- CSR aggregation, 256-dim, fused norm+bias+relu+JK ----------------

__global__ __launch_bounds__(256) void k_agg(const float* __restrict__ proj,
                                             const int* __restrict__ row_ptr,
                                             const int* __restrict__ csr_src,
                                             const float* __restrict__ norm_in,
                                             const float* __restrict__ bias,
                                             float* __restrict__ h_out,
                                             float* __restrict__ jk, int mode) {
  __shared__ int elist[256];
  int n = blockIdx.x;
  int c = threadIdx.x;
  int s = row_ptr[n], e = row_ptr[n + 1];
  float acc0 = 0.f, acc1 = 0.f;
  for (int basei = s; basei < e; basei += 256) {
    int cnt = min(256, e - basei);
    __syncthreads();
    if (c < cnt) elist[c] = csr_src[basei + c];
    __syncthreads();
    int j = 0;
    for (; j + 1 < cnt; j += 2) {
      int u0 = elist[j], u1 = elist[j + 1];
      acc0 += proj[(size_t)u0 * 256 + c];
      acc1 += proj[(size_t)u1 * 256 + c];
    }
    if (j < cnt) acc0 += proj[(size_t)elist[j] * 256 + c];
  }
  float v = (acc0 + acc1) * norm_in[n] + bias[c];
  v = fmaxf(v, 0.f);
  h_out[(size_t)n * 256 + c] = v;
  if (mode == 0) jk[(size_t)n * 256 + c] = v;
  else           jk[(size_t)n * 256 + c] = fmaxf(jk[(size_t)n * 256 + c], v);
}

// ---------------- final 40-dim aggregation + log_softmax ----------------

__global__ __launch_bounds__(64) void k_agg_out(const float* __restrict__ proj,
                                                const int* __restrict__ row_ptr,
                                                const int* __restrict__ csr_src,
                                                const float* __restrict__ norm_in,
                                                const float* __restrict__ b_out,
                                                float* __restrict__ out) {
  int n = blockIdx.x;
  int c = threadIdx.x;  // 64 threads, cols 0..39 live
  int s = row_ptr[n], e = row_ptr[n + 1];
  float acc = 0.f;
  for (int i = s; i < e; ++i) {
    acc += proj[(size_t)csr_src[i] * 64 + c];
  }
  float v = acc * norm_in[n] + ((c < 40) ? b_out[c] : 0.f);
  float vm = (c < 40) ? v : -3.0e38f;
  float m = vm;
#pragma unroll
  for (int o = 32; o > 0; o >>= 1) m = fmaxf(m, __shfl_xor(m, o, 64));
  float ex = (c < 40) ? __expf(v - m) : 0.f;
  float ssum = ex;
#pragma unroll
  for (int o = 32; o > 0; o >>= 1) ssum += __shfl_xor(ssum, o, 64);
  float lse = m + logf(ssum);
  if (c < 40) out[(size_t)n * 40 + c] = v - lse;
}

// ---------------- launch ----------------

extern "C" void kernel_launch(void* const* d_in, const int* in_sizes, int n_in,
                              void* d_out, int out_size, void* d_ws, size_t ws_size,
                              hipStream_t stream) {
  const float* feats = (const float*)d_in[0];
  const int*   src   = (const int*)d_in[1];
  const int*   dst   = (const int*)d_in[2];
  const float* W0    = (const float*)d_in[3];
  const float* b0    = (const float*)d_in[4];
  const float* Ws    = (const float*)d_in[5];
  const float* bs    = (const float*)d_in[6];
  const float* W_out = (const float*)d_in[7];
  const float* b_out = (const float*)d_in[8];
  float* out = (float*)d_out;

  char* base = (char*)d_ws;
  size_t off = 0;
  auto alloc = [&](size_t bytes) -> void* {
    off = (off + 255) & ~(size_t)255;
    void* r = base + off;
    off += bytes;
    return r;
  };
  float* norm_out = (float*)alloc((size_t)N_NODES * 4);
  float* norm_in  = (float*)alloc((size_t)N_NODES * 4);
  int*   deg_out  = (int*)alloc((size_t)N_NODES * 4);
  int*   deg_in   = (int*)alloc((size_t)N_NODES * 4);
  int*   cursor   = (int*)alloc((size_t)N_NODES * 4);
  int*   row_ptr  = (int*)alloc((size_t)(N_NODES + 1) * 4);
  int*   csr_src  = (int*)alloc((size_t)N_EDGES * 4);
  u16*   Wt0h     = (u16*)alloc((size_t)256 * 512 * 2);
  u16*   Wt0l     = (u16*)alloc((size_t)256 * 512 * 2);
  u16*   Wtsh     = (u16*)alloc((size_t)5 * 256 * 256 * 2);
  u16*   Wtsl     = (u16*)alloc((size_t)5 * 256 * 256 * 2);
  u16*   Wtoh     = (u16*)alloc((size_t)128 * 256 * 2);
  u16*   Wtol     = (u16*)alloc((size_t)128 * 256 * 2);
  float* proj40   = (float*)alloc((size_t)N_NODES * 64 * 4);
  float* bufA     = (float*)alloc((size_t)N_NODES * 256 * 4);
  float* bufB     = (float*)alloc((size_t)N_NODES * 256 * 4);
  float* jk       = (float*)alloc((size_t)N_NODES * 256 * 4);
  (void)ws_size; (void)in_sizes; (void)n_in; (void)out_size;

  hipMemsetAsync(deg_out, 0, (size_t)N_NODES * 4, stream);
  hipMemsetAsync(deg_in,  0, (size_t)N_NODES * 4, stream);
  hipMemsetAsync(cursor,  0, (size_t)N_NODES * 4, stream);

  k_count<<<2048, 256, 0, stream>>>(src, dst, deg_out, deg_in);
  k_norms<<<(N_NODES + 255) / 256, 256, 0, stream>>>(deg_out, deg_in, norm_out, norm_in);
  k_scan<<<1, 1024, 0, stream>>>(deg_in, row_ptr);
  k_fill<<<2048, 256, 0, stream>>>(src, dst, row_ptr, cursor, csr_src);

  k_wsplit<<<(256 * 512 + 255) / 256, 256, 0, stream>>>(W0, 512, 256, 256, Wt0h, Wt0l);
  for (int ll = 0; ll < 5; ++ll)
    k_wsplit<<<(256 * 256 + 255) / 256, 256, 0, stream>>>(
        Ws + (size_t)ll * 256 * 256, 256, 256, 256,
        Wtsh + (size_t)ll * 256 * 256, Wtsl + (size_t)ll * 256 * 256);
  k_wsplit<<<(128 * 256 + 255) / 256, 256, 0, stream>>>(W_out, 256, 40, 128, Wtoh, Wtol);

  dim3 gg((N_NODES + 127) / 128, 2);
  // layer 0 (K=512)
  k_gemm_mfma<<<gg, 256, 0, stream>>>(feats, 512, Wt0h, Wt0l, norm_out, bufB, 256, N_NODES, 256);
  k_agg<<<N_NODES, 256, 0, stream>>>(bufB, row_ptr, csr_src, norm_in, b0, bufA, jk, 0);
  // layers 1..5 (K=256)
  for (int ll = 0; ll < 5; ++ll) {
    k_gemm_mfma<<<gg, 256, 0, stream>>>(bufA, 256, Wtsh + (size_t)ll * 256 * 256,
                                        Wtsl + (size_t)ll * 256 * 256, norm_out,
                                        bufB, 256, N_NODES, 256);
    k_agg<<<N_NODES, 256, 0, stream>>>(bufB, row_ptr, csr_src, norm_in,
                                       bs + (size_t)ll * 256, bufA, jk, 1);
  }
  // final: jk @ W_out (transposed+split, padded to 128 cols), aggregate, log_softmax
  dim3 gf((N_NODES + 127) / 128, 1);
  k_gemm_mfma<<<gf, 256, 0, stream>>>(jk, 256, Wtoh, Wtol, norm_out, proj40, 64, N_NODES, 64);
  k_agg_out<<<N_NODES, 64, 0, stream>>>(proj40, row_ptr, csr_src, norm_in, b_out, out);
}